// Round 1
// baseline (1001.009 us; speedup 1.0000x reference)
//
#include <hip/hip_runtime.h>

// GNN_MLP: 2-layer add-aggregate GNN + mean pool + MLP head.
// Key algebra: conv = segsum((h@W+b)[src], dst) = segsum(h[src])@W + indeg*b
// -> conv1 aggregates raw 2-float x instead of 16-float messages.

#define TPB 256

__device__ __forceinline__ void atomAddF(float* p, float v) {
    unsafeAtomicAdd(p, v);   // native global_atomic_add_f32 on gfx950
}

__device__ __forceinline__ float reluf(float v) { return v > 0.f ? v : 0.f; }

// K0: aggx = x (self-loop contribution), deg = 0
__global__ void k0_init(const float* __restrict__ x, float* __restrict__ aggx,
                        int* __restrict__ deg, int N) {
    int i = blockIdx.x * blockDim.x + threadIdx.x;
    if (i < N) {
        ((float2*)aggx)[i] = ((const float2*)x)[i];
        deg[i] = 0;
    }
}

// K1: per-edge scatter of raw features (2 floats) + degree count
__global__ void k1_edge2(const int* __restrict__ src, const int* __restrict__ dst,
                         const float* __restrict__ x, float* __restrict__ aggx,
                         int* __restrict__ deg, int E) {
    int e = blockIdx.x * blockDim.x + threadIdx.x;
    if (e < E) {
        int s = src[e], d = dst[e];
        float2 xv = ((const float2*)x)[s];
        atomAddF(&aggx[2 * d],     xv.x);
        atomAddF(&aggx[2 * d + 1], xv.y);
        atomicAdd(&deg[d], 1);
    }
}

// K2: h1 = relu(aggx@W1 + indeg*b1);  agg1 initialized with h1 (self-loop)
__global__ void k2_h1(const float* __restrict__ aggx, const int* __restrict__ deg,
                      const float* __restrict__ W1, const float* __restrict__ b1,
                      float* __restrict__ h1, float* __restrict__ agg1, int N) {
    int i = blockIdx.x * blockDim.x + threadIdx.x;
    if (i < N) {
        float a0 = aggx[2 * i], a1 = aggx[2 * i + 1];
        float degf = (float)(deg[i] + 1);
        float h[16];
#pragma unroll
        for (int j = 0; j < 16; j++) {
            float v = fmaf(a0, W1[j], fmaf(a1, W1[16 + j], degf * b1[j]));
            h[j] = reluf(v);
        }
        float4* h1v = (float4*)(h1 + 16 * (size_t)i);
        float4* agv = (float4*)(agg1 + 16 * (size_t)i);
#pragma unroll
        for (int q = 0; q < 4; q++) {
            float4 t = make_float4(h[4 * q], h[4 * q + 1], h[4 * q + 2], h[4 * q + 3]);
            h1v[q] = t;
            agv[q] = t;
        }
    }
}

// K3: per-edge scatter of h1 (16 floats); 4 threads/edge, 4 floats each
__global__ void k3_edge16(const int* __restrict__ src, const int* __restrict__ dst,
                          const float* __restrict__ h1, float* __restrict__ agg1, int E) {
    int t = blockIdx.x * blockDim.x + threadIdx.x;
    int e = t >> 2, p = t & 3;
    if (e < E) {
        int s = src[e], d = dst[e];
        float4 v = ((const float4*)(h1 + 16 * (size_t)s))[p];
        float* out = agg1 + 16 * (size_t)d + 4 * p;
        atomAddF(out + 0, v.x);
        atomAddF(out + 1, v.y);
        atomAddF(out + 2, v.z);
        atomAddF(out + 3, v.w);
    }
}

// K4: h2 = relu(agg1@W2 + indeg*b2), stored to global [N,32]
__global__ void k4_h2(const float* __restrict__ agg1, const int* __restrict__ deg,
                      const float* __restrict__ W2, const float* __restrict__ b2,
                      float* __restrict__ h2, int N) {
    int i = blockIdx.x * blockDim.x + threadIdx.x;
    if (i < N) {
        float a[16];
        const float4* av = (const float4*)(agg1 + 16 * (size_t)i);
#pragma unroll
        for (int q = 0; q < 4; q++) {
            float4 t = av[q];
            a[4 * q] = t.x; a[4 * q + 1] = t.y; a[4 * q + 2] = t.z; a[4 * q + 3] = t.w;
        }
        float degf = (float)(deg[i] + 1);
        float4* ov = (float4*)(h2 + 32 * (size_t)i);
        for (int q = 0; q < 8; q++) {
            float4 r;
            float* rp = &r.x;
#pragma unroll
            for (int jj = 0; jj < 4; jj++) {
                int j = 4 * q + jj;
                float v = degf * b2[j];
#pragma unroll
                for (int k = 0; k < 16; k++) v = fmaf(a[k], W2[k * 32 + j], v);
                rp[jj] = reluf(v);
            }
            ov[q] = r;
        }
    }
}

__device__ __forceinline__ int lower_bound(const int* __restrict__ a, int n, int v) {
    int lo = 0, hi = n;
    while (lo < hi) {
        int m = (lo + hi) >> 1;
        if (a[m] < v) lo = m + 1; else hi = m;
    }
    return lo;
}

// K5: mean pool per graph. batch is sorted -> binary search range, no atomics.
// One block (256 thr = 8 node-lanes x 32 features) per graph.
__global__ void k5_pool(const float* __restrict__ h2, const int* __restrict__ batch,
                        float* __restrict__ pooled, int N) {
    int g = blockIdx.x;
    int lo = lower_bound(batch, N, g);
    int hi = lower_bound(batch, N, g + 1);
    int cnt = hi - lo;
    int f = threadIdx.x & 31;
    int r = threadIdx.x >> 5;
    float acc = 0.f;
    for (int n = lo + r; n < hi; n += 8)
        acc += h2[32 * (size_t)n + f];
    __shared__ float s[8][32];
    s[r][f] = acc;
    __syncthreads();
    if (r == 0) {
        float t = 0.f;
#pragma unroll
        for (int q = 0; q < 8; q++) t += s[q][f];
        pooled[32 * g + f] = t / (float)(cnt > 1 ? cnt : 1);
    }
}

// K6: final MLP, one thread per graph
__global__ void k6_mlp(const float* __restrict__ pooled,
                       const float* __restrict__ Wf1, const float* __restrict__ bf1,
                       const float* __restrict__ Wf2, const float* __restrict__ bf2,
                       float* __restrict__ out, int G) {
    int g = blockIdx.x * blockDim.x + threadIdx.x;
    if (g < G) {
        float p[32];
#pragma unroll
        for (int i = 0; i < 32; i++) p[i] = pooled[32 * g + i];
        float acc = bf2[0];
#pragma unroll
        for (int j = 0; j < 16; j++) {
            float v = bf1[j];
#pragma unroll
            for (int i = 0; i < 32; i++) v = fmaf(p[i], Wf1[i * 16 + j], v);
            acc = fmaf(reluf(v), Wf2[j], acc);
        }
        out[g] = acc;
    }
}

extern "C" void kernel_launch(void* const* d_in, const int* in_sizes, int n_in,
                              void* d_out, int out_size, void* d_ws, size_t ws_size,
                              hipStream_t stream) {
    const float* x    = (const float*)d_in[0];
    const int*   ei   = (const int*)d_in[1];
    const int*   batch= (const int*)d_in[2];
    const float* W1   = (const float*)d_in[3];
    const float* b1   = (const float*)d_in[4];
    const float* W2   = (const float*)d_in[5];
    const float* b2   = (const float*)d_in[6];
    const float* Wf1  = (const float*)d_in[7];
    const float* bf1  = (const float*)d_in[8];
    const float* Wf2  = (const float*)d_in[9];
    const float* bf2  = (const float*)d_in[10];
    float* out = (float*)d_out;

    const int N = in_sizes[0] / 2;
    const int E = in_sizes[1] / 2;
    const int G = out_size;
    const int* src = ei;        // edge_index[0]
    const int* dst = ei + E;    // edge_index[1]

    // workspace layout (16B aligned blocks)
    char* w = (char*)d_ws;
    float* aggx   = (float*)w;                       w += (size_t)N * 2 * sizeof(float);
    int*   deg    = (int*)w;                         w += (size_t)N * sizeof(int);
    float* h1     = (float*)w;                       w += (size_t)N * 16 * sizeof(float);
    float* agg1   = (float*)w;                       w += (size_t)N * 16 * sizeof(float);
    float* h2     = (float*)w;                       w += (size_t)N * 32 * sizeof(float);
    float* pooled = (float*)w;                       w += (size_t)G * 32 * sizeof(float);

    int nb_n = (N + TPB - 1) / TPB;
    int nb_e = (E + TPB - 1) / TPB;
    int nb_e4 = (4 * E + TPB - 1) / TPB;

    k0_init  <<<nb_n, TPB, 0, stream>>>(x, aggx, deg, N);
    k1_edge2 <<<nb_e, TPB, 0, stream>>>(src, dst, x, aggx, deg, E);
    k2_h1    <<<nb_n, TPB, 0, stream>>>(aggx, deg, W1, b1, h1, agg1, N);
    k3_edge16<<<nb_e4, TPB, 0, stream>>>(src, dst, h1, agg1, E);
    k4_h2    <<<nb_n, TPB, 0, stream>>>(agg1, deg, W2, b2, h2, N);
    k5_pool  <<<G, TPB, 0, stream>>>(h2, batch, pooled, N);
    k6_mlp   <<<(G + TPB - 1) / TPB, TPB, 0, stream>>>(pooled, Wf1, bf1, Wf2, bf2, out, G);
}

// Round 2
// 545.859 us; speedup vs baseline: 1.8338x; 1.8338x over previous
//
#include <hip/hip_runtime.h>

// GNN_MLP: 2-layer add-aggregate GNN + mean pool + MLP head.
// R2: CSR-gather instead of scatter-atomics. Per-launch CSR build
// (histogram + scan + cursor scatter, int atomics only), then both convs
// are per-node gathers; zero float atomics. Pool+MLP fused per graph.
//
// Algebra: conv = segsum((h@W+b)[src], dst) = segsum(h[src])@W + indeg*b
// -> conv1 aggregates raw 2-float x, matmul applied once per node.

#define TPB 256
#define SCAN_ITEMS 2048   // 256 threads x 8 items

__device__ __forceinline__ float reluf(float v) { return v > 0.f ? v : 0.f; }

__global__ void kZero(int* __restrict__ p, int n) {
    int i = blockIdx.x * blockDim.x + threadIdx.x;
    if (i < n) p[i] = 0;
}

// degree histogram over dst
__global__ void kHist(const int* __restrict__ dst, int* __restrict__ deg, int E) {
    int e = blockIdx.x * blockDim.x + threadIdx.x;
    if (e < E) atomicAdd(&deg[dst[e]], 1);
}

// scan pass A: per-block sums of deg
__global__ void kScanA(const int* __restrict__ deg, int* __restrict__ blockSums, int N) {
    int base = blockIdx.x * SCAN_ITEMS + threadIdx.x * 8;
    int s = 0;
#pragma unroll
    for (int k = 0; k < 8; k++) { int i = base + k; if (i < N) s += deg[i]; }
    __shared__ int sm[256];
    sm[threadIdx.x] = s; __syncthreads();
    for (int off = 128; off > 0; off >>= 1) {
        if (threadIdx.x < off) sm[threadIdx.x] += sm[threadIdx.x + off];
        __syncthreads();
    }
    if (threadIdx.x == 0) blockSums[blockIdx.x] = sm[0];
}

// scan pass B: serial exclusive scan of block sums (nb ~ 245, trivial)
__global__ void kScanB(int* __restrict__ blockSums, int nb) {
    if (threadIdx.x == 0 && blockIdx.x == 0) {
        int acc = 0;
        for (int i = 0; i < nb; i++) { int v = blockSums[i]; blockSums[i] = acc; acc += v; }
    }
}

// scan pass C: final exclusive scan -> row_start, cursor
__global__ void kScanC(const int* __restrict__ deg, const int* __restrict__ blockSums,
                       int* __restrict__ row_start, int* __restrict__ cursor, int N, int E) {
    int base = blockIdx.x * SCAN_ITEMS + threadIdx.x * 8;
    int v[8]; int s = 0;
#pragma unroll
    for (int k = 0; k < 8; k++) { int i = base + k; v[k] = (i < N) ? deg[i] : 0; s += v[k]; }
    __shared__ int sm[256];
    sm[threadIdx.x] = s; __syncthreads();
    for (int off = 1; off < 256; off <<= 1) {
        int t = (threadIdx.x >= (unsigned)off) ? sm[threadIdx.x - off] : 0;
        __syncthreads();
        sm[threadIdx.x] += t;
        __syncthreads();
    }
    int excl = sm[threadIdx.x] - s + blockSums[blockIdx.x];
#pragma unroll
    for (int k = 0; k < 8; k++) {
        int i = base + k;
        if (i < N) { row_start[i] = excl; cursor[i] = excl; excl += v[k]; }
    }
    if (blockIdx.x == 0 && threadIdx.x == 0) row_start[N] = E;
}

// bucket src ids by dst
__global__ void kScatter(const int* __restrict__ src, const int* __restrict__ dst,
                         int* __restrict__ cursor, int* __restrict__ csr, int E) {
    int e = blockIdx.x * blockDim.x + threadIdx.x;
    if (e < E) {
        int pos = atomicAdd(&cursor[dst[e]], 1);
        csr[pos] = src[e];
    }
}

// conv1: gather raw x over CSR row (+self), then W1 matmul + relu -> h1
__global__ void kConv1(const float* __restrict__ x, const int* __restrict__ csr,
                       const int* __restrict__ row_start,
                       const float* __restrict__ W1, const float* __restrict__ b1,
                       float* __restrict__ h1, int N) {
    int i = blockIdx.x * blockDim.x + threadIdx.x;
    if (i >= N) return;
    int rs = row_start[i], re = row_start[i + 1];
    float2 self = ((const float2*)x)[i];
    float a0 = self.x, a1 = self.y;
    for (int e = rs; e < re; e++) {
        float2 xv = ((const float2*)x)[csr[e]];
        a0 += xv.x; a1 += xv.y;
    }
    float degf = (float)(re - rs + 1);
    float4* ov = (float4*)(h1 + 16 * (size_t)i);
#pragma unroll
    for (int q = 0; q < 4; q++) {
        float4 r;
        float* rp = &r.x;
#pragma unroll
        for (int jj = 0; jj < 4; jj++) {
            int j = 4 * q + jj;
            rp[jj] = reluf(fmaf(a0, W1[j], fmaf(a1, W1[16 + j], degf * b1[j])));
        }
        ov[q] = r;
    }
}

// conv2: gather h1 (16f) over CSR row (+self), then W2 matmul + relu -> h2
__global__ void kConv2(const float* __restrict__ h1, const int* __restrict__ csr,
                       const int* __restrict__ row_start,
                       const float* __restrict__ W2, const float* __restrict__ b2,
                       float* __restrict__ h2, int N) {
    int i = blockIdx.x * blockDim.x + threadIdx.x;
    if (i >= N) return;
    int rs = row_start[i], re = row_start[i + 1];
    const float4* sv = (const float4*)(h1 + 16 * (size_t)i);
    float4 a0 = sv[0], a1 = sv[1], a2 = sv[2], a3 = sv[3];
    for (int e = rs; e < re; e++) {
        const float4* p = (const float4*)(h1 + 16 * (size_t)csr[e]);
        float4 q0 = p[0], q1 = p[1], q2 = p[2], q3 = p[3];
        a0.x += q0.x; a0.y += q0.y; a0.z += q0.z; a0.w += q0.w;
        a1.x += q1.x; a1.y += q1.y; a1.z += q1.z; a1.w += q1.w;
        a2.x += q2.x; a2.y += q2.y; a2.z += q2.z; a2.w += q2.w;
        a3.x += q3.x; a3.y += q3.y; a3.z += q3.z; a3.w += q3.w;
    }
    float a[16] = {a0.x,a0.y,a0.z,a0.w, a1.x,a1.y,a1.z,a1.w,
                   a2.x,a2.y,a2.z,a2.w, a3.x,a3.y,a3.z,a3.w};
    float degf = (float)(re - rs + 1);
    float4* ov = (float4*)(h2 + 32 * (size_t)i);
#pragma unroll
    for (int q = 0; q < 8; q++) {
        float4 r;
        float* rp = &r.x;
#pragma unroll
        for (int jj = 0; jj < 4; jj++) {
            int j = 4 * q + jj;
            float v = degf * b2[j];
#pragma unroll
            for (int k = 0; k < 16; k++) v = fmaf(a[k], W2[k * 32 + j], v);
            rp[jj] = reluf(v);
        }
        ov[q] = r;
    }
}

__device__ __forceinline__ int lower_bound(const int* __restrict__ a, int n, int v) {
    int lo = 0, hi = n;
    while (lo < hi) {
        int m = (lo + hi) >> 1;
        if (a[m] < v) lo = m + 1; else hi = m;
    }
    return lo;
}

// mean pool per graph (batch sorted -> binary search range) + fused MLP head
__global__ void kPoolMLP(const float* __restrict__ h2, const int* __restrict__ batch,
                         const float* __restrict__ Wf1, const float* __restrict__ bf1,
                         const float* __restrict__ Wf2, const float* __restrict__ bf2,
                         float* __restrict__ out, int N) {
    int g = blockIdx.x;
    int lo = lower_bound(batch, N, g);
    int hi = lower_bound(batch, N, g + 1);
    int cnt = hi - lo;
    int f = threadIdx.x & 31;
    int r = threadIdx.x >> 5;
    float acc = 0.f;
    for (int n = lo + r; n < hi; n += 8)
        acc += h2[32 * (size_t)n + f];
    __shared__ float s[8][32];
    __shared__ float p[32];
    __shared__ float v16[16];
    s[r][f] = acc;
    __syncthreads();
    if (r == 0) {
        float t = 0.f;
#pragma unroll
        for (int q = 0; q < 8; q++) t += s[q][f];
        p[f] = t / (float)(cnt > 1 ? cnt : 1);
    }
    __syncthreads();
    if (threadIdx.x < 16) {
        int j = threadIdx.x;
        float v = bf1[j];
#pragma unroll
        for (int i = 0; i < 32; i++) v = fmaf(p[i], Wf1[i * 16 + j], v);
        v16[j] = reluf(v);
    }
    __syncthreads();
    if (threadIdx.x == 0) {
        float a = bf2[0];
#pragma unroll
        for (int j = 0; j < 16; j++) a = fmaf(v16[j], Wf2[j], a);
        out[g] = a;
    }
}

static inline size_t align256(size_t v) { return (v + 255) & ~(size_t)255; }

extern "C" void kernel_launch(void* const* d_in, const int* in_sizes, int n_in,
                              void* d_out, int out_size, void* d_ws, size_t ws_size,
                              hipStream_t stream) {
    const float* x    = (const float*)d_in[0];
    const int*   ei   = (const int*)d_in[1];
    const int*   batch= (const int*)d_in[2];
    const float* W1   = (const float*)d_in[3];
    const float* b1   = (const float*)d_in[4];
    const float* W2   = (const float*)d_in[5];
    const float* b2   = (const float*)d_in[6];
    const float* Wf1  = (const float*)d_in[7];
    const float* bf1  = (const float*)d_in[8];
    const float* Wf2  = (const float*)d_in[9];
    const float* bf2  = (const float*)d_in[10];
    float* out = (float*)d_out;

    const int N = in_sizes[0] / 2;
    const int E = in_sizes[1] / 2;
    const int G = out_size;
    const int* src = ei;        // edge_index[0]
    const int* dst = ei + E;    // edge_index[1]

    const int nbScan = (N + SCAN_ITEMS - 1) / SCAN_ITEMS;

    // workspace layout, each region 256B-aligned
    char* w = (char*)d_ws;
    int*   deg       = (int*)w;   w += align256((size_t)N * sizeof(int));
    int*   row_start = (int*)w;   w += align256((size_t)(N + 1) * sizeof(int));
    int*   cursor    = (int*)w;   w += align256((size_t)N * sizeof(int));
    int*   blockSums = (int*)w;   w += align256((size_t)nbScan * sizeof(int));
    int*   csr       = (int*)w;   w += align256((size_t)E * sizeof(int));
    float* h1        = (float*)w; w += align256((size_t)N * 16 * sizeof(float));
    float* h2        = (float*)w; w += align256((size_t)N * 32 * sizeof(float));

    int nb_n = (N + TPB - 1) / TPB;
    int nb_e = (E + TPB - 1) / TPB;

    kZero   <<<nb_n, TPB, 0, stream>>>(deg, N);
    kHist   <<<nb_e, TPB, 0, stream>>>(dst, deg, E);
    kScanA  <<<nbScan, TPB, 0, stream>>>(deg, blockSums, N);
    kScanB  <<<1, 64, 0, stream>>>(blockSums, nbScan);
    kScanC  <<<nbScan, TPB, 0, stream>>>(deg, blockSums, row_start, cursor, N, E);
    kScatter<<<nb_e, TPB, 0, stream>>>(src, dst, cursor, csr, E);
    kConv1  <<<nb_n, TPB, 0, stream>>>(x, csr, row_start, W1, b1, h1, N);
    kConv2  <<<nb_n, TPB, 0, stream>>>(h1, csr, row_start, W2, b2, h2, N);
    kPoolMLP<<<G, TPB, 0, stream>>>(h2, batch, Wf1, bf1, Wf2, bf2, out, N);
}

// Round 3
// 444.132 us; speedup vs baseline: 2.2539x; 1.2290x over previous
//
#include <hip/hip_runtime.h>

// GNN_MLP R3: coarse bucket-partition (512 nodes/bucket) + LDS-accumulate convs.
// No per-node CSR, no float global atomics, no random 4B global scatter.
// Algebra: conv = segsum((h@W+b)[src],dst) = segsum(h[src])@W + indeg*b.

#define TPB 256
#define BKT_BITS 9
#define BKT 512               // nodes per bucket
#define MAXB 1024             // max buckets (requires N < 524288)
#define PE 16384              // edges per partition block

__device__ __forceinline__ float reluf(float v) { return v > 0.f ? v : 0.f; }

// per-block LDS histogram over dst buckets -> global bucket counts
__global__ void kHistB(const int* __restrict__ dst, int* __restrict__ bcount, int E) {
    __shared__ int h[MAXB];
    for (int i = threadIdx.x; i < MAXB; i += TPB) h[i] = 0;
    __syncthreads();
    int base = blockIdx.x * PE;
    int end = base + PE < E ? base + PE : E;
    for (int e = base + threadIdx.x; e < end; e += TPB)
        atomicAdd(&h[dst[e] >> BKT_BITS], 1);
    __syncthreads();
    for (int i = threadIdx.x; i < MAXB; i += TPB) {
        int c = h[i];
        if (c) atomicAdd(&bcount[i], c);
    }
}

// parallel exclusive scan of 1024 bucket counts (one block, 1024 threads)
__global__ void kScan(const int* __restrict__ bcount, int* __restrict__ bbase,
                      int* __restrict__ cursor) {
    __shared__ int s[MAXB];
    int t = threadIdx.x;
    int v = bcount[t];
    s[t] = v;
    __syncthreads();
    for (int off = 1; off < MAXB; off <<= 1) {
        int u = (t >= off) ? s[t - off] : 0;
        __syncthreads();
        s[t] += u;
        __syncthreads();
    }
    int excl = s[t] - v;
    bbase[t] = excl;
    cursor[t] = excl;
    if (t == MAXB - 1) bbase[MAXB] = s[t];
}

// partition scatter: pack (src<<9 | dst&511) into bucket-contiguous regions.
// Per-block reservation -> each block's run per bucket is ~64B (one line).
__global__ void kPart(const int* __restrict__ src, const int* __restrict__ dst,
                      int* __restrict__ cursor, int* __restrict__ part, int E) {
    __shared__ int h[MAXB];
    for (int i = threadIdx.x; i < MAXB; i += TPB) h[i] = 0;
    __syncthreads();
    int base = blockIdx.x * PE;
    int end = base + PE < E ? base + PE : E;
    for (int e = base + threadIdx.x; e < end; e += TPB)
        atomicAdd(&h[dst[e] >> BKT_BITS], 1);
    __syncthreads();
    for (int i = threadIdx.x; i < MAXB; i += TPB) {
        int c = h[i];
        if (c) h[i] = atomicAdd(&cursor[i], c);
    }
    __syncthreads();
    for (int e = base + threadIdx.x; e < end; e += TPB) {
        int d = dst[e];
        int b = d >> BKT_BITS;
        int pos = atomicAdd(&h[b], 1);
        part[pos] = (src[e] << BKT_BITS) | (d & (BKT - 1));
    }
}

// conv1: one block per bucket; LDS-accumulate raw x (2f) + degree, then W1+relu.
__global__ void kConv1B(const float* __restrict__ x, const int* __restrict__ part,
                        const int* __restrict__ bbase,
                        const float* __restrict__ W1, const float* __restrict__ b1,
                        float* __restrict__ h1, int* __restrict__ deg, int N) {
    __shared__ float ax[BKT * 2];
    __shared__ int cnt[BKT];
    int b = blockIdx.x, node0 = b << BKT_BITS;
    for (int i = threadIdx.x; i < BKT; i += TPB) { ax[2 * i] = 0.f; ax[2 * i + 1] = 0.f; cnt[i] = 0; }
    __syncthreads();
    int rs = bbase[b], re = bbase[b + 1];
    for (int e = rs + threadIdx.x; e < re; e += TPB) {
        int w = part[e];
        int s = w >> BKT_BITS, l = w & (BKT - 1);
        float2 xv = ((const float2*)x)[s];
        atomicAdd(&ax[2 * l], xv.x);
        atomicAdd(&ax[2 * l + 1], xv.y);
        atomicAdd(&cnt[l], 1);
    }
    __syncthreads();
    for (int l = threadIdx.x; l < BKT; l += TPB) {
        int i = node0 + l;
        if (i >= N) continue;
        float2 s2 = ((const float2*)x)[i];
        float a0 = ax[2 * l] + s2.x, a1 = ax[2 * l + 1] + s2.y;
        int indeg = cnt[l] + 1;            // + self loop
        float degf = (float)indeg;
        float4* ov = (float4*)(h1 + 16 * (size_t)i);
#pragma unroll
        for (int q = 0; q < 4; q++) {
            float4 r;
            float* rp = &r.x;
#pragma unroll
            for (int jj = 0; jj < 4; jj++) {
                int j = 4 * q + jj;
                rp[jj] = reluf(fmaf(a0, W1[j], fmaf(a1, W1[16 + j], degf * b1[j])));
            }
            ov[q] = r;
        }
        deg[i] = indeg;
    }
}

// conv2: one block per bucket; LDS-accumulate h1 (16f/node, 32KB), then W2+relu -> h2.
__global__ void kConv2B(const float* __restrict__ h1, const int* __restrict__ part,
                        const int* __restrict__ bbase, const int* __restrict__ deg,
                        const float* __restrict__ W2, const float* __restrict__ b2,
                        float* __restrict__ h2, int N) {
    __shared__ float acc[BKT * 16];   // 32 KB
    int b = blockIdx.x, node0 = b << BKT_BITS;
    for (int i = threadIdx.x; i < BKT * 16; i += TPB) acc[i] = 0.f;
    __syncthreads();
    int rs = bbase[b], re = bbase[b + 1];
    for (int e = rs + threadIdx.x; e < re; e += TPB) {
        int w = part[e];
        int s = w >> BKT_BITS, l = w & (BKT - 1);
        const float4* p = (const float4*)(h1 + 16 * (size_t)s);
        float4 q0 = p[0], q1 = p[1], q2 = p[2], q3 = p[3];
        float* a = &acc[l * 16];
        atomicAdd(a + 0,  q0.x); atomicAdd(a + 1,  q0.y);
        atomicAdd(a + 2,  q0.z); atomicAdd(a + 3,  q0.w);
        atomicAdd(a + 4,  q1.x); atomicAdd(a + 5,  q1.y);
        atomicAdd(a + 6,  q1.z); atomicAdd(a + 7,  q1.w);
        atomicAdd(a + 8,  q2.x); atomicAdd(a + 9,  q2.y);
        atomicAdd(a + 10, q2.z); atomicAdd(a + 11, q2.w);
        atomicAdd(a + 12, q3.x); atomicAdd(a + 13, q3.y);
        atomicAdd(a + 14, q3.z); atomicAdd(a + 15, q3.w);
    }
    __syncthreads();
    for (int l = threadIdx.x; l < BKT; l += TPB) {
        int i = node0 + l;
        if (i >= N) continue;
        const float4* sv = (const float4*)(h1 + 16 * (size_t)i);
        float a[16];
        const float* al = &acc[l * 16];
#pragma unroll
        for (int q = 0; q < 4; q++) {
            float4 t = sv[q];
            a[4 * q]     = al[4 * q]     + t.x;
            a[4 * q + 1] = al[4 * q + 1] + t.y;
            a[4 * q + 2] = al[4 * q + 2] + t.z;
            a[4 * q + 3] = al[4 * q + 3] + t.w;
        }
        float degf = (float)deg[i];
        float4* ov = (float4*)(h2 + 32 * (size_t)i);
#pragma unroll
        for (int q = 0; q < 8; q++) {
            float4 r;
            float* rp = &r.x;
#pragma unroll
            for (int jj = 0; jj < 4; jj++) {
                int j = 4 * q + jj;
                float v = degf * b2[j];
#pragma unroll
                for (int k = 0; k < 16; k++) v = fmaf(a[k], W2[k * 32 + j], v);
                rp[jj] = reluf(v);
            }
            ov[q] = r;
        }
    }
}

__device__ __forceinline__ int lower_bound(const int* __restrict__ a, int n, int v) {
    int lo = 0, hi = n;
    while (lo < hi) {
        int m = (lo + hi) >> 1;
        if (a[m] < v) lo = m + 1; else hi = m;
    }
    return lo;
}

// mean pool per graph (batch sorted -> binary search range) + fused MLP head
__global__ void kPoolMLP(const float* __restrict__ h2, const int* __restrict__ batch,
                         const float* __restrict__ Wf1, const float* __restrict__ bf1,
                         const float* __restrict__ Wf2, const float* __restrict__ bf2,
                         float* __restrict__ out, int N) {
    int g = blockIdx.x;
    int lo = lower_bound(batch, N, g);
    int hi = lower_bound(batch, N, g + 1);
    int cnt = hi - lo;
    int f = threadIdx.x & 31;
    int r = threadIdx.x >> 5;
    float acc = 0.f;
    for (int n = lo + r; n < hi; n += 8)
        acc += h2[32 * (size_t)n + f];
    __shared__ float s[8][32];
    __shared__ float p[32];
    __shared__ float v16[16];
    s[r][f] = acc;
    __syncthreads();
    if (r == 0) {
        float t = 0.f;
#pragma unroll
        for (int q = 0; q < 8; q++) t += s[q][f];
        p[f] = t / (float)(cnt > 1 ? cnt : 1);
    }
    __syncthreads();
    if (threadIdx.x < 16) {
        int j = threadIdx.x;
        float v = bf1[j];
#pragma unroll
        for (int i = 0; i < 32; i++) v = fmaf(p[i], Wf1[i * 16 + j], v);
        v16[j] = reluf(v);
    }
    __syncthreads();
    if (threadIdx.x == 0) {
        float a = bf2[0];
#pragma unroll
        for (int j = 0; j < 16; j++) a = fmaf(v16[j], Wf2[j], a);
        out[g] = a;
    }
}

static inline size_t align256(size_t v) { return (v + 255) & ~(size_t)255; }

extern "C" void kernel_launch(void* const* d_in, const int* in_sizes, int n_in,
                              void* d_out, int out_size, void* d_ws, size_t ws_size,
                              hipStream_t stream) {
    const float* x    = (const float*)d_in[0];
    const int*   ei   = (const int*)d_in[1];
    const int*   batch= (const int*)d_in[2];
    const float* W1   = (const float*)d_in[3];
    const float* b1   = (const float*)d_in[4];
    const float* W2   = (const float*)d_in[5];
    const float* b2   = (const float*)d_in[6];
    const float* Wf1  = (const float*)d_in[7];
    const float* bf1  = (const float*)d_in[8];
    const float* Wf2  = (const float*)d_in[9];
    const float* bf2  = (const float*)d_in[10];
    float* out = (float*)d_out;

    const int N = in_sizes[0] / 2;
    const int E = in_sizes[1] / 2;
    const int G = out_size;
    const int* src = ei;        // edge_index[0]
    const int* dst = ei + E;    // edge_index[1]

    // workspace layout, 256B-aligned regions
    char* w = (char*)d_ws;
    int*   bcount = (int*)w;   w += align256((size_t)MAXB * sizeof(int));
    int*   bbase  = (int*)w;   w += align256((size_t)(MAXB + 1) * sizeof(int));
    int*   cursor = (int*)w;   w += align256((size_t)MAXB * sizeof(int));
    int*   part   = (int*)w;   w += align256((size_t)E * sizeof(int));
    int*   deg    = (int*)w;   w += align256((size_t)N * sizeof(int));
    float* h1     = (float*)w; w += align256((size_t)N * 16 * sizeof(float));
    float* h2     = (float*)w; w += align256((size_t)N * 32 * sizeof(float));

    const int nbE = (E + PE - 1) / PE;
    const int nbB = (N + BKT - 1) / BKT;

    hipMemsetAsync(bcount, 0, MAXB * sizeof(int), stream);
    kHistB <<<nbE, TPB, 0, stream>>>(dst, bcount, E);
    kScan  <<<1, MAXB, 0, stream>>>(bcount, bbase, cursor);
    kPart  <<<nbE, TPB, 0, stream>>>(src, dst, cursor, part, E);
    kConv1B<<<nbB, TPB, 0, stream>>>(x, part, bbase, W1, b1, h1, deg, N);
    kConv2B<<<nbB, TPB, 0, stream>>>(h1, part, bbase, deg, W2, b2, h2, N);
    kPoolMLP<<<G, TPB, 0, stream>>>(h2, batch, Wf1, bf1, Wf2, bf2, out, N);
}